// Round 3
// baseline (480.734 us; speedup 1.0000x reference)
//
#include <hip/hip_runtime.h>
#include <hip/hip_bf16.h>
#include <hip/hip_fp16.h>
#include <math.h>

#define Bn 16
#define Nn 2048
#define Cn 128

typedef __attribute__((ext_vector_type(8))) short bf16x8;   // 8 bf16 = 4 VGPRs
typedef __attribute__((ext_vector_type(4))) float f32x4;

// 0.5 / (sqrt(128) * 1.5)  -- folds symmetrization 0.5 and temperature
constexpr float SCALE = 0.029462782549439476f;
constexpr float SHIFT = 4.0f;  // fixed softmax shift; logits bounded well below this +88

__device__ __forceinline__ const bf16x8* as_frag(const void* p){
    return reinterpret_cast<const bf16x8*>(p);
}

// async global->LDS, 16B per lane. LDS dest = wave-uniform base + lane*16 (HW).
__device__ __forceinline__ void load16_lds(const void* g, void* l){
    __builtin_amdgcn_global_load_lds(
        (const __attribute__((address_space(1))) void*)g,
        (__attribute__((address_space(3))) void*)l,
        16, 0, 0);
}

// --- fused prep: combined bias (fp16) for all blocks; first 64 blocks also
//     transpose W [d][c] -> WT [c][d] so the projection kernel reads coalesced.
__global__ __launch_bounds__(256) void prep_kernel(
    const float* __restrict__ A, const float* __restrict__ M, __half* __restrict__ CB,
    const float* __restrict__ Wq, const float* __restrict__ Wk,
    float* __restrict__ WqT, float* __restrict__ WkT)
{
    size_t idx = (size_t)blockIdx.x * 256 + threadIdx.x;
    int n = (int)(idx >> 11), m = (int)(idx & (Nn-1));
    float a = A[idx];
    float mm = M[idx];
    float v = (mm <= 0.0f || n == m) ? -INFINITY : a;
    CB[idx] = __float2half(v);
    if (blockIdx.x < 64) {
        int widx = (int)idx;            // 0..16383
        int d = widx >> 7, c = widx & 127;
        WqT[c*Cn + d] = Wq[widx];
        WkT[c*Cn + d] = Wk[widx];
    }
}

// --- Q/K projection: fp32 accumulate, bf16 store. 32 rows per block. ---
__global__ __launch_bounds__(256) void qk_kernel(
    const float* __restrict__ H, const float* __restrict__ WqT, const float* __restrict__ WkT,
    __hip_bfloat16* __restrict__ Qb, __hip_bfloat16* __restrict__ Kb)
{
    __shared__ __align__(16) float Hs[32*Cn];
    const int t = threadIdx.x;
    const size_t row0 = (size_t)blockIdx.x * 32;
    const float4* src = reinterpret_cast<const float4*>(H + row0*Cn);
    float4* dst = reinterpret_cast<float4*>(Hs);
    #pragma unroll
    for (int i = 0; i < 4; i++) dst[i*256 + t] = src[i*256 + t];
    __syncthreads();
    const int d = t & 127, rh = t >> 7;
    float accq[16], acck[16];
    #pragma unroll
    for (int r = 0; r < 16; r++){ accq[r] = 0.f; acck[r] = 0.f; }
    for (int cb = 0; cb < Cn; cb += 4){
        float wq[4], wk[4];
        #pragma unroll
        for (int j = 0; j < 4; j++){ wq[j] = WqT[(cb+j)*Cn + d]; wk[j] = WkT[(cb+j)*Cn + d]; }
        #pragma unroll
        for (int r = 0; r < 16; r++){
            float4 h = *reinterpret_cast<const float4*>(&Hs[(rh*16+r)*Cn + cb]);
            accq[r] += h.x*wq[0] + h.y*wq[1] + h.z*wq[2] + h.w*wq[3];
            acck[r] += h.x*wk[0] + h.y*wk[1] + h.z*wk[2] + h.w*wk[3];
        }
    }
    #pragma unroll
    for (int r = 0; r < 16; r++){
        size_t row = row0 + rh*16 + r;
        Qb[row*Cn + d] = __float2bfloat16(accq[r]);
        Kb[row*Cn + d] = __float2bfloat16(acck[r]);
    }
}

// =====================================================================
// FUSED attention: block = 64 rows x ALL 2048 cols -> row sums are
// block-local. Loop1: e = exp(sym-logit - SHIFT) -> fp16 temp Et +
// register row sums. Reduce to rsinv in LDS. Loop2: re-read own Et tile
// (L2/L3-hot), scale, write fp32 out. No second MFMA pass, no global
// rowsum round-trip, one kernel instead of two.
// LDS tiles K/Q: linear [64][256B], XOR-swizzled contents (chunk^ (row&7)),
// staged by global_load_lds from pre-swizzled global addresses.
// =====================================================================
__global__ __launch_bounds__(256) void attn_fused_kernel(
    const __hip_bfloat16* __restrict__ Qb, const __hip_bfloat16* __restrict__ Kb,
    const __half* __restrict__ CB, __half* __restrict__ Et, float* __restrict__ out)
{
    __shared__ __align__(16) char Ks_s[64*256];
    __shared__ __align__(16) char Qs_s[64*256];
    __shared__ float rsinv_s[64];
    const int t = threadIdx.x;
    const int wave = t >> 6, lane = t & 63;
    const int q = lane >> 4, lc = lane & 15;
    const int batch = blockIdx.y;
    const int n0 = blockIdx.x * 64;
    const size_t rbase = (size_t)batch * Nn;

    // A-operand fragments: wave owns 16 rows; lane holds row lc, k = ks*32+q*8..+7
    const int nA = n0 + wave*16 + lc;
    bf16x8 aQ[4], aK[4];
    #pragma unroll
    for (int ks = 0; ks < 4; ks++){
        aQ[ks] = *as_frag(Qb + (rbase + nA)*Cn + ks*32 + q*8);
        aK[ks] = *as_frag(Kb + (rbase + nA)*Cn + ks*32 + q*8);
    }

    int nout[4];
    #pragma unroll
    for (int r = 0; r < 4; r++) nout[r] = n0 + wave*16 + q*4 + r;  // C/D row = q*4+reg

    float sumacc[4] = {0.f,0.f,0.f,0.f};

    // staging lane constants (see R2): src chunk = cw ^ (lane>>4) ^ (4*(idx&1))
    const int laneoffE = ((lane >> 4) << 8) + ((((lane & 15) ^ (lane >> 4))) << 4);
    int coff[4];
    #pragma unroll
    for (int ks = 0; ks < 4; ks++) coff[ks] = (((4*ks + q) ^ (lc & 7)) << 4);
    const int rowoff = lc * 256;

    const char* gt0 = (wave < 2) ? (const char*)Kb : (const char*)Qb;
    void* lt = (wave < 2) ? (void*)Ks_s : (void*)Qs_s;
    const int idx0 = (wave & 1) * 8;

    for (int mc = 0; mc < Nn/64; mc++){
        __syncthreads();   // prev iter's LDS reads done before overwrite
        {   // stage 64 m-rows of K and Q (16 KB each = 16 x 1KB issues, 8 per wave)
            const size_t tileoff = (rbase + (size_t)mc*64) * (Cn*2);
            const char* gt = gt0 + tileoff;
            #pragma unroll
            for (int j = 0; j < 8; j++){
                const int idx = idx0 + j;
                const int lo = laneoffE ^ ((j & 1) << 6);   // idx&1 == j&1 (idx0 even)
                load16_lds(gt + idx*1024 + lo, (char*)lt + idx*1024);
            }
        }
        __syncthreads();   // implies vmcnt(0): staged data visible
        #pragma unroll
        for (int mt = 0; mt < 4; mt++){
            const int m0 = mc*64 + mt*16;
            bf16x8 bK[4], bQ[4];
            #pragma unroll
            for (int ks = 0; ks < 4; ks++){
                bK[ks] = *as_frag(Ks_s + mt*4096 + rowoff + coff[ks]);
                bQ[ks] = *as_frag(Qs_s + mt*4096 + rowoff + coff[ks]);
            }
            // acc[n][m] = Qn.Km + Kn.Qm  (symmetrization folded in)
            f32x4 acc = {0.f,0.f,0.f,0.f};
            #pragma unroll
            for (int ks = 0; ks < 4; ks++){
                acc = __builtin_amdgcn_mfma_f32_16x16x32_bf16(aQ[ks], bK[ks], acc, 0, 0, 0);
                acc = __builtin_amdgcn_mfma_f32_16x16x32_bf16(aK[ks], bQ[ks], acc, 0, 0, 0);
            }
            const int m = m0 + lc;   // C/D col = lane&15
            #pragma unroll
            for (int r = 0; r < 4; r++){
                const int n = nout[r];
                float logit = fmaf(acc[r], SCALE, __half2float(CB[(size_t)n*Nn + m]));
                float e = __expf(logit - SHIFT);   // -inf -> 0
                sumacc[r] += e;
                Et[(rbase + n)*Nn + m] = __float2half(e);   // unnormalized, fp16
            }
        }
    }
    // block-local row sums -> reciprocals in LDS
    #pragma unroll
    for (int r = 0; r < 4; r++){
        float s = sumacc[r];
        s += __shfl_xor(s, 1);
        s += __shfl_xor(s, 2);
        s += __shfl_xor(s, 4);
        s += __shfl_xor(s, 8);
        if (lc == 0) rsinv_s[wave*16 + q*4 + r] = 1.0f / s;
    }
    __syncthreads();   // drains vmcnt(0): all Et stores of this block visible

    // loop2: normalize own 64x2048 tile. Reads 8B/lane coalesced, writes 16B/lane.
    const __half* srcT = Et + (rbase + n0) * Nn;
    float* dstT = out + (rbase + n0) * Nn;
    #pragma unroll 2
    for (int r = 0; r < 64; r++){
        const float rs = rsinv_s[r];
        const __half2* s2 = reinterpret_cast<const __half2*>(srcT + (size_t)r * Nn);
        float4* d4 = reinterpret_cast<float4*>(dstT + (size_t)r * Nn);
        #pragma unroll
        for (int h = 0; h < 2; h++){
            const int c4 = h*256 + t;            // float4 index within row (0..511)
            __half2 a = s2[c4*2];
            __half2 b = s2[c4*2 + 1];
            float2 fa = __half22float2(a), fb = __half22float2(b);
            float4 o; o.x = fa.x*rs; o.y = fa.y*rs; o.z = fb.x*rs; o.w = fb.y*rs;
            d4[c4] = o;
        }
    }
}

// --- fallback (ws too small for Et): R2 two-pass attention ---
template<int PASS>
__global__ __launch_bounds__(256) void attn2_kernel(
    const __hip_bfloat16* __restrict__ Qb, const __hip_bfloat16* __restrict__ Kb,
    const __half* __restrict__ CB, float* __restrict__ rowsum, float* __restrict__ out)
{
    __shared__ __align__(16) char Ks_s[64*256];
    __shared__ __align__(16) char Qs_s[64*256];
    const int t = threadIdx.x;
    const int wave = t >> 6, lane = t & 63;
    const int q = lane >> 4, lc = lane & 15;
    const int rb = blockIdx.x & 15, ch = blockIdx.x >> 4;
    const int batch = blockIdx.y;
    const int n0 = rb * 128;
    const size_t rbase = (size_t)batch * Nn;

    bf16x8 aQ[2][4], aK[2][4];
    #pragma unroll
    for (int g = 0; g < 2; g++){
        const int nA = n0 + wave*32 + g*16 + lc;
        #pragma unroll
        for (int ks = 0; ks < 4; ks++){
            aQ[g][ks] = *as_frag(Qb + (rbase + nA)*Cn + ks*32 + q*8);
            aK[g][ks] = *as_frag(Kb + (rbase + nA)*Cn + ks*32 + q*8);
        }
    }
    int nout[2][4];
    #pragma unroll
    for (int g = 0; g < 2; g++)
        #pragma unroll
        for (int r = 0; r < 4; r++) nout[g][r] = n0 + wave*32 + g*16 + q*4 + r;

    float rs_inv[2][4];
    if (PASS == 1){
        #pragma unroll
        for (int g = 0; g < 2; g++)
            #pragma unroll
            for (int r = 0; r < 4; r++){
                float s = rowsum[rbase + nout[g][r]] + rowsum[(size_t)Bn*Nn + rbase + nout[g][r]];
                rs_inv[g][r] = 1.0f / s;
            }
    }
    float sumacc[2][4] = {{0.f,0.f,0.f,0.f},{0.f,0.f,0.f,0.f}};

    const int laneoffE = ((lane >> 4) << 8) + ((((lane & 15) ^ (lane >> 4))) << 4);
    int coff[4];
    #pragma unroll
    for (int ks = 0; ks < 4; ks++) coff[ks] = (((4*ks + q) ^ (lc & 7)) << 4);
    const int rowoff = lc * 256;

    const char* gt0 = (wave < 2) ? (const char*)Kb : (const char*)Qb;
    void* lt = (wave < 2) ? (void*)Ks_s : (void*)Qs_s;
    const int idx0 = (wave & 1) * 8;

    const int mc0 = ch * (Nn/128);
    for (int mc = mc0; mc < mc0 + Nn/128; mc++){
        __syncthreads();
        {
            const size_t tileoff = (rbase + (size_t)mc*64) * (Cn*2);
            const char* gt = gt0 + tileoff;
            #pragma unroll
            for (int j = 0; j < 8; j++){
                const int idx = idx0 + j;
                const int lo = laneoffE ^ ((j & 1) << 6);
                load16_lds(gt + idx*1024 + lo, (char*)lt + idx*1024);
            }
        }
        __syncthreads();
        #pragma unroll
        for (int mt = 0; mt < 4; mt++){
            const int m0 = mc*64 + mt*16;
            bf16x8 bK[4], bQ[4];
            #pragma unroll
            for (int ks = 0; ks < 4; ks++){
                bK[ks] = *as_frag(Ks_s + mt*4096 + rowoff + coff[ks]);
                bQ[ks] = *as_frag(Qs_s + mt*4096 + rowoff + coff[ks]);
            }
            const int m = m0 + lc;
            #pragma unroll
            for (int g = 0; g < 2; g++){
                f32x4 acc = {0.f,0.f,0.f,0.f};
                #pragma unroll
                for (int ks = 0; ks < 4; ks++){
                    acc = __builtin_amdgcn_mfma_f32_16x16x32_bf16(aQ[g][ks], bK[ks], acc, 0, 0, 0);
                    acc = __builtin_amdgcn_mfma_f32_16x16x32_bf16(aK[g][ks], bQ[ks], acc, 0, 0, 0);
                }
                #pragma unroll
                for (int r = 0; r < 4; r++){
                    const int n = nout[g][r];
                    float logit = fmaf(acc[r], SCALE, __half2float(CB[(size_t)n*Nn + m]));
                    float e = __expf(logit - SHIFT);
                    if (PASS == 0) sumacc[g][r] += e;
                    else out[(rbase + n)*Nn + m] = e * rs_inv[g][r];
                }
            }
        }
    }
    if (PASS == 0){
        float* rs = rowsum + (size_t)ch * (Bn*Nn);
        #pragma unroll
        for (int g = 0; g < 2; g++)
            #pragma unroll
            for (int r = 0; r < 4; r++){
                float s = sumacc[g][r];
                s += __shfl_xor(s, 1);
                s += __shfl_xor(s, 2);
                s += __shfl_xor(s, 4);
                s += __shfl_xor(s, 8);
                if (lc == 0) rs[rbase + nout[g][r]] = s;
            }
    }
}

// ws layout (bytes):
//   [0,        8388608)    Qb   bf16 [B*N, C]
//   [8388608,  16777216)   Kb   bf16 [B*N, C]
//   [16777216, 16842752)   WqT  fp32 [C, C]
//   [16842752, 16908288)   WkT  fp32 [C, C]
//   [16908288, 25296896)   CB   fp16 [N, N]
//   [25296896, 159514624)  Et   fp16 [B*N, N]   (fused path)
//   [25296896, 26345472)   rowsum fp32 [2][B*N] (fallback path)
extern "C" void kernel_launch(void* const* d_in, const int* in_sizes, int n_in,
                              void* d_out, int out_size, void* d_ws, size_t ws_size,
                              hipStream_t stream)
{
    const float* H  = (const float*)d_in[0];
    const float* A  = (const float*)d_in[1];
    const float* M  = (const float*)d_in[2];
    const float* Wq = (const float*)d_in[3];
    const float* Wk = (const float*)d_in[4];
    float* out = (float*)d_out;
    char* ws = (char*)d_ws;
    __hip_bfloat16* Qb = (__hip_bfloat16*)(ws + 0);
    __hip_bfloat16* Kb = (__hip_bfloat16*)(ws + 8388608);
    float* WqT         = (float*)(ws + 16777216);
    float* WkT         = (float*)(ws + 16842752);
    __half* CB         = (__half*)(ws + 16908288);

    prep_kernel<<<(Nn*Nn)/256, 256, 0, stream>>>(A, M, CB, Wq, Wk, WqT, WkT);
    qk_kernel<<<(Bn*Nn)/32, 256, 0, stream>>>(H, WqT, WkT, Qb, Kb);

    const size_t NEEDED = 25296896ull + (size_t)Bn*Nn*Nn*2;   // ~159.5 MB
    if (ws_size >= NEEDED){
        __half* Et = (__half*)(ws + 25296896);
        attn_fused_kernel<<<dim3(Nn/64, Bn), 256, 0, stream>>>(Qb, Kb, CB, Et, out);
    } else {
        float* rowsum = (float*)(ws + 25296896);
        attn2_kernel<0><<<dim3(32, Bn), 256, 0, stream>>>(Qb, Kb, CB, rowsum, out);
        attn2_kernel<1><<<dim3(32, Bn), 256, 0, stream>>>(Qb, Kb, CB, rowsum, out);
    }
}

// Round 4
// 439.172 us; speedup vs baseline: 1.0946x; 1.0946x over previous
//
#include <hip/hip_runtime.h>
#include <hip/hip_bf16.h>
#include <hip/hip_fp16.h>
#include <math.h>

#define Bn 16
#define Nn 2048
#define Cn 128

typedef __attribute__((ext_vector_type(8))) short bf16x8;   // 8 bf16 = 4 VGPRs
typedef __attribute__((ext_vector_type(4))) float f32x4;

// 0.5 / (sqrt(128) * 1.5)  -- folds symmetrization 0.5 and temperature
constexpr float SCALE = 0.029462782549439476f;
constexpr float SHIFT = 4.0f;  // fixed softmax shift; logits bounded well below this +88

__device__ __forceinline__ const bf16x8* as_frag(const void* p){
    return reinterpret_cast<const bf16x8*>(p);
}

// async global->LDS, 16B per lane. LDS dest = wave-uniform base + lane*16 (HW).
__device__ __forceinline__ void load16_lds(const void* g, void* l){
    __builtin_amdgcn_global_load_lds(
        (const __attribute__((address_space(1))) void*)g,
        (__attribute__((address_space(3))) void*)l,
        16, 0, 0);
}

// --- fused prep: combined bias (fp16) for all blocks; first 64 blocks also
//     transpose W [d][c] -> WT [c][d] so the projection kernel reads coalesced.
__global__ __launch_bounds__(256) void prep_kernel(
    const float* __restrict__ A, const float* __restrict__ M, __half* __restrict__ CB,
    const float* __restrict__ Wq, const float* __restrict__ Wk,
    float* __restrict__ WqT, float* __restrict__ WkT)
{
    size_t idx = (size_t)blockIdx.x * 256 + threadIdx.x;
    int n = (int)(idx >> 11), m = (int)(idx & (Nn-1));
    float a = A[idx];
    float mm = M[idx];
    float v = (mm <= 0.0f || n == m) ? -INFINITY : a;
    CB[idx] = __float2half(v);
    if (blockIdx.x < 64) {
        int widx = (int)idx;            // 0..16383
        int d = widx >> 7, c = widx & 127;
        WqT[c*Cn + d] = Wq[widx];
        WkT[c*Cn + d] = Wk[widx];
    }
}

// --- Q/K projection: fp32 accumulate, bf16 store. 32 rows per block. ---
__global__ __launch_bounds__(256) void qk_kernel(
    const float* __restrict__ H, const float* __restrict__ WqT, const float* __restrict__ WkT,
    __hip_bfloat16* __restrict__ Qb, __hip_bfloat16* __restrict__ Kb)
{
    __shared__ __align__(16) float Hs[32*Cn];
    const int t = threadIdx.x;
    const size_t row0 = (size_t)blockIdx.x * 32;
    const float4* src = reinterpret_cast<const float4*>(H + row0*Cn);
    float4* dst = reinterpret_cast<float4*>(Hs);
    #pragma unroll
    for (int i = 0; i < 4; i++) dst[i*256 + t] = src[i*256 + t];
    __syncthreads();
    const int d = t & 127, rh = t >> 7;
    float accq[16], acck[16];
    #pragma unroll
    for (int r = 0; r < 16; r++){ accq[r] = 0.f; acck[r] = 0.f; }
    for (int cb = 0; cb < Cn; cb += 4){
        float wq[4], wk[4];
        #pragma unroll
        for (int j = 0; j < 4; j++){ wq[j] = WqT[(cb+j)*Cn + d]; wk[j] = WkT[(cb+j)*Cn + d]; }
        #pragma unroll
        for (int r = 0; r < 16; r++){
            float4 h = *reinterpret_cast<const float4*>(&Hs[(rh*16+r)*Cn + cb]);
            accq[r] += h.x*wq[0] + h.y*wq[1] + h.z*wq[2] + h.w*wq[3];
            acck[r] += h.x*wk[0] + h.y*wk[1] + h.z*wk[2] + h.w*wk[3];
        }
    }
    #pragma unroll
    for (int r = 0; r < 16; r++){
        size_t row = row0 + rh*16 + r;
        Qb[row*Cn + d] = __float2bfloat16(accq[r]);
        Kb[row*Cn + d] = __float2bfloat16(acck[r]);
    }
}

// =====================================================================
// ONE-PASS attention, e kept in registers.
// Block = 512 threads = 8 waves, owns 32 rows x all 2048 cols.
//   wave = qt*2 + rg : qt = column quarter (512 cols), rg = row group (16 rows).
// Per wave: 16 rows x 512 cols -> per-thread e = 128 fp16 packed in 64 uints.
// Loop: stage 64-col K/Q chunk per quarter (wave rg=0 stages K, rg=1 stages Q),
//   MFMA sym-logits, exp -> pack e, accumulate row sums in registers.
// Then: shuffle-reduce + cross-quarter LDS reduce -> 1/rowsum, scale
//   in-register e, write out. No temp buffer, no recompute, no 2nd pass.
// LDS tiles: linear [64][256B], XOR-swizzled contents (chunk ^ (row&7)),
// staged by global_load_lds from pre-swizzled global addresses (rule 21).
// =====================================================================
__global__ __launch_bounds__(512, 2) void attn_onepass_kernel(
    const __hip_bfloat16* __restrict__ Qb, const __hip_bfloat16* __restrict__ Kb,
    const __half* __restrict__ CB, float* __restrict__ out)
{
    __shared__ __align__(16) char tiles[4][2][16384];  // [quarter][K/Q][64 rows * 256 B]
    __shared__ float psum[4][32];                      // [quarter][row in block]
    const int t = threadIdx.x;
    const int wave = t >> 6, lane = t & 63;
    const int q = lane >> 4, lc = lane & 15;
    const int qt = wave >> 1;          // column quarter 0..3
    const int rg = wave & 1;           // row group 0/1

    // XCD swizzle: group same-batch rowblocks on one XCD (K/Q L2 reuse).
    // 1024 blocks, 1024%8==0 -> simple bijective form.
    const int h = blockIdx.x;
    const int logical = (h & 7) * 128 + (h >> 3);
    const int bx = logical & 63;       // rowblock 0..63
    const int by = logical >> 6;       // batch 0..15
    const int n0 = bx * 32;
    const size_t rbase = (size_t)by * Nn;

    // A-operand fragments: wave's 16 rows; lane holds row lc, k = ks*32+q*8..+7
    const int nA = n0 + rg*16 + lc;
    bf16x8 aQ[4], aK[4];
    #pragma unroll
    for (int ks = 0; ks < 4; ks++){
        aQ[ks] = *as_frag(Qb + (rbase + nA)*Cn + ks*32 + q*8);
        aK[ks] = *as_frag(Kb + (rbase + nA)*Cn + ks*32 + q*8);
    }

    int nout[4];
    #pragma unroll
    for (int r = 0; r < 4; r++) nout[r] = n0 + rg*16 + q*4 + r;  // C/D row = q*4+reg

    // staging lane constants (verified R2): src chunk = cw ^ (lane>>4) ^ (4*(idx&1))
    const int laneoffE = ((lane >> 4) << 8) + ((((lane & 15) ^ (lane >> 4))) << 4);
    // read-side: chunk(ks) = (4*ks + q) ^ (lc&7)
    int coff[4];
    #pragma unroll
    for (int ks = 0; ks < 4; ks++) coff[ks] = (((4*ks + q) ^ (lc & 7)) << 4);
    const int rowoff = lc * 256;

    const char* gsrc0 = rg ? (const char*)Qb : (const char*)Kb;  // rg=0 stages K, rg=1 stages Q
    char* ldst = tiles[qt][rg];

    unsigned int ep[4][16];            // packed fp16 e: [r][mtg/2], .lo=even mtg, .hi=odd
    float sumacc[4] = {0.f,0.f,0.f,0.f};

    #pragma unroll
    for (int mc = 0; mc < 8; mc++){    // 8 chunks of 64 cols per quarter
        __syncthreads();               // prev chunk's LDS reads done before overwrite
        const size_t tileoff = (rbase + (size_t)qt*512 + (size_t)mc*64) * (Cn*2);
        const char* gt = gsrc0 + tileoff;
        #pragma unroll
        for (int idx = 0; idx < 16; idx++){
            const int lo = laneoffE ^ ((idx & 1) << 6);
            load16_lds(gt + idx*1024 + lo, ldst + idx*1024);
        }
        __syncthreads();               // implies vmcnt(0): staged data visible
        #pragma unroll
        for (int mt = 0; mt < 4; mt++){
            const int mtg = mc*4 + mt;                 // 0..31, compile-time
            bf16x8 bK[4], bQ[4];
            #pragma unroll
            for (int ks = 0; ks < 4; ks++){
                bK[ks] = *as_frag(tiles[qt][0] + mt*4096 + rowoff + coff[ks]);
                bQ[ks] = *as_frag(tiles[qt][1] + mt*4096 + rowoff + coff[ks]);
            }
            // acc[n][m] = Qn.Km + Kn.Qm  (symmetrization folded in)
            f32x4 acc = {0.f,0.f,0.f,0.f};
            #pragma unroll
            for (int ks = 0; ks < 4; ks++){
                acc = __builtin_amdgcn_mfma_f32_16x16x32_bf16(aQ[ks], bK[ks], acc, 0, 0, 0);
                acc = __builtin_amdgcn_mfma_f32_16x16x32_bf16(aK[ks], bQ[ks], acc, 0, 0, 0);
            }
            const int m = qt*512 + mtg*16 + lc;        // C/D col = lane&15
            #pragma unroll
            for (int r = 0; r < 4; r++){
                float logit = fmaf(acc[r], SCALE, __half2float(CB[(size_t)nout[r]*Nn + m]));
                float e = __expf(logit - SHIFT);       // -inf -> 0
                sumacc[r] += e;
                unsigned int he = (unsigned int)__half_as_ushort(__float2half(e));
                if ((mtg & 1) == 0) ep[r][mtg>>1] = he;
                else                ep[r][mtg>>1] |= (he << 16);
            }
        }
    }

    // row sums: reduce over lc (16 cols groups) then across the 4 quarters via LDS
    #pragma unroll
    for (int r = 0; r < 4; r++){
        float s = sumacc[r];
        s += __shfl_xor(s, 1);
        s += __shfl_xor(s, 2);
        s += __shfl_xor(s, 4);
        s += __shfl_xor(s, 8);
        if (lc == 0) psum[qt][rg*16 + q*4 + r] = s;
    }
    __syncthreads();
    float rs[4];
    #pragma unroll
    for (int r = 0; r < 4; r++){
        const int rl = rg*16 + q*4 + r;
        rs[r] = 1.0f / (psum[0][rl] + psum[1][rl] + psum[2][rl] + psum[3][rl]);
    }

    // normalize from registers and write out (16-lane groups hit full 64-B lines)
    #pragma unroll
    for (int r = 0; r < 4; r++){
        float* orow = out + (rbase + nout[r])*Nn + qt*512 + lc;
        #pragma unroll
        for (int k = 0; k < 16; k++){
            const unsigned int p = ep[r][k];
            const float elo = __half2float(__ushort_as_half((unsigned short)(p & 0xFFFFu)));
            const float ehi = __half2float(__ushort_as_half((unsigned short)(p >> 16)));
            orow[(2*k)*16]   = elo * rs[r];
            orow[(2*k+1)*16] = ehi * rs[r];
        }
    }
}

// ws layout (bytes):
//   [0,        8388608)    Qb   bf16 [B*N, C]
//   [8388608,  16777216)   Kb   bf16 [B*N, C]
//   [16777216, 16842752)   WqT  fp32 [C, C]
//   [16842752, 16908288)   WkT  fp32 [C, C]
//   [16908288, 25296896)   CB   fp16 [N, N]
extern "C" void kernel_launch(void* const* d_in, const int* in_sizes, int n_in,
                              void* d_out, int out_size, void* d_ws, size_t ws_size,
                              hipStream_t stream)
{
    const float* H  = (const float*)d_in[0];
    const float* A  = (const float*)d_in[1];
    const float* M  = (const float*)d_in[2];
    const float* Wq = (const float*)d_in[3];
    const float* Wk = (const float*)d_in[4];
    float* out = (float*)d_out;
    char* ws = (char*)d_ws;
    __hip_bfloat16* Qb = (__hip_bfloat16*)(ws + 0);
    __hip_bfloat16* Kb = (__hip_bfloat16*)(ws + 8388608);
    float* WqT         = (float*)(ws + 16777216);
    float* WkT         = (float*)(ws + 16842752);
    __half* CB         = (__half*)(ws + 16908288);

    prep_kernel<<<(Nn*Nn)/256, 256, 0, stream>>>(A, M, CB, Wq, Wk, WqT, WkT);
    qk_kernel<<<(Bn*Nn)/32, 256, 0, stream>>>(H, WqT, WkT, Qb, Kb);
    attn_onepass_kernel<<<dim3((Nn/32) * Bn), 512, 0, stream>>>(Qb, Kb, CB, out);
}